// Round 9
// baseline (491.065 us; speedup 1.0000x reference)
//
#include <hip/hip_runtime.h>
#include <stdint.h>

// AttentionReadout: G=1024 x N=64, D=512, H=8, hd=64. fp32 I/O, bf16 MFMA.
// v9: ctx = P@V is NEVER materialized. Everything downstream of PV is linear
// in ctx, so:  logit = P.(V.u) ; wctx = V^T.(P^T.gate).  P stays in pA frags
// (16 regs), V in vB frags (32 regs); the y/t vectors distribute across lanes
// exactly matching the fragment m-indices (reduce over l15, use per (ks2,q,j)).
// Kills the 64-reg cacc (v8 spill source) AND 32 PV MFMAs per wave.
// 2 blocks/CU, 4 waves/SIMD, peak live ~96 regs. Fused out-proj GEMV epilogue.

typedef __attribute__((ext_vector_type(8))) short short8;   // 8 bf16
typedef __attribute__((ext_vector_type(4))) float f32x4;    // MFMA C/D frag

#define D_ 512

// ---- ws layout (bytes) ----
#define WQKV_OFF   0u          // 1536*512 bf16 = 1572864
#define WO_OFF     1572864u    // 512*512 bf16  = 524288
#define UPART_OFF  2097152u    // 16*512 f32    = 32768
#define U_OFF      2129920u    // 512 f32       = 2048
#define C0_OFF     2131968u    // 64

__device__ __forceinline__ unsigned short f2bf(float f) {
    union { float f; unsigned int u; } t; t.f = f;
    unsigned int u = t.u;
    return (unsigned short)((u + 0x7FFFu + ((u >> 16) & 1u)) >> 16);  // RNE
}
__device__ __forceinline__ unsigned pack2(float a, float b) {
    return (unsigned)f2bf(a) | ((unsigned)f2bf(b) << 16);
}
__device__ __forceinline__ float blo(unsigned v) {
    union { unsigned u; float f; } t; t.u = v << 16; return t.f;
}
__device__ __forceinline__ float bhi(unsigned v) {
    union { unsigned u; float f; } t; t.u = v & 0xFFFF0000u; return t.f;
}

// ---- pre-pass 1 (merged): blocks 0..1023 convert weights; 1024..1039 u-partials ----
__global__ __launch_bounds__(256)
void convert_and_u(const float* __restrict__ wqkv, const float* __restrict__ wo,
                   const float* __restrict__ gw,
                   unsigned short* __restrict__ wbf, float* __restrict__ upart) {
    const int b = blockIdx.x;
    const int t = threadIdx.x;
    if (b < 1024) {
        const int i4 = b * 256 + t;          // 262144 float4 total
        float4 v;
        if (i4 < 196608) v = *(const float4*)(wqkv + (size_t)i4 * 4);
        else             v = *(const float4*)(wo   + (size_t)(i4 - 196608) * 4);
        uint2 p; p.x = pack2(v.x, v.y); p.y = pack2(v.z, v.w);
        *(uint2*)(wbf + (size_t)i4 * 4) = p;
    } else {
        const int bb = b - 1024;             // 16 blocks
        float a0 = 0.f, a1 = 0.f;
        #pragma unroll 4
        for (int e = bb * 32; e < bb * 32 + 32; ++e) {
            const float ge = gw[e];
            a0 += wo[(size_t)e * 512 + t]       * ge;
            a1 += wo[(size_t)e * 512 + t + 256] * ge;
        }
        upart[bb * 512 + t] = a0; upart[bb * 512 + t + 256] = a1;
    }
}

// ---- pre-pass 2: u = sum partials; c0 = bo.gw + gb ----
__global__ __launch_bounds__(256)
void finalize_u(const float* __restrict__ upart, const float* __restrict__ bo,
                const float* __restrict__ gw, const float* __restrict__ gb,
                float* __restrict__ u, float* __restrict__ c0) {
    const int t = threadIdx.x;
    float s0 = 0.f, s1 = 0.f;
    #pragma unroll
    for (int b = 0; b < 16; ++b) { s0 += upart[b*512 + t]; s1 += upart[b*512 + t + 256]; }
    u[t] = s0; u[t + 256] = s1;
    __shared__ float rb[256];
    rb[t] = bo[t] * gw[t] + bo[t + 256] * gw[t + 256];
    __syncthreads();
    for (int s = 128; s > 0; s >>= 1) { if (t < s) rb[t] += rb[t + s]; __syncthreads(); }
    if (t == 0) c0[0] = rb[0] + gb[0];
}

union U8 { unsigned u[4]; short8 s; };

// ---- main: per-graph, wave-per-head, no ctx, fused out-proj ----
__global__ __launch_bounds__(512, 4)
void attn_full_kernel(const float* __restrict__ x,             // [65536,512] f32
                      const unsigned short* __restrict__ wqkv, // [1536,512] bf16
                      const float* __restrict__ bqkv,          // [1536] f32
                      const unsigned short* __restrict__ wo_bf,// [512,512] bf16
                      const float* __restrict__ bo,            // [512] f32
                      const float* __restrict__ u,             // [512] f32
                      const float* __restrict__ c0,            // [1] f32
                      float* __restrict__ out)                 // [1024,512] f32
{
    __shared__ unsigned short xs[64][520];     // 66560 B; epilogue overlays wctx
    __shared__ float logitp[8][64];            // 2048 B
    __shared__ float gatev[64];                // 256 B
    __shared__ float sgs;                      // 4 B
    // total ~68.9 KB -> 2 blocks/CU, 16 waves/CU (4/SIMD)

    const int g    = blockIdx.x;
    const int tid  = threadIdx.x;
    const int w    = tid >> 6;      // wave = head
    const int lane = tid & 63;
    const int l15  = lane & 15;
    const int quad = lane >> 4;

    // ---- stage x once: fp32 -> bf16 LDS ----
    #pragma unroll
    for (int i = 0; i < 16; ++i) {
        int idx = tid + i * 512;
        int row = idx >> 7;
        int c4  = idx & 127;
        float4 v = *(const float4*)(x + ((size_t)(g*64 + row))*512 + c4*4);
        uint2 p; p.x = pack2(v.x, v.y); p.y = pack2(v.z, v.w);
        *(uint2*)(&xs[row][c4*4]) = p;
    }
    __syncthreads();

    const int h = w;

    // ======== pass-A: q,k (K=512) -> score frags in-register ========
    U8 qA[4][2], kB[4][2];   // [n-strip][ks2]
    #pragma unroll
    for (int dt = 0; dt < 4; ++dt) {
        f32x4 aq[4], ak[4];
        #pragma unroll
        for (int nt = 0; nt < 4; ++nt) {
            aq[nt] = (f32x4){0.f,0.f,0.f,0.f};
            ak[nt] = (f32x4){0.f,0.f,0.f,0.f};
        }
        const unsigned short* wq = wqkv + (size_t)(       h*64 + dt*16 + l15) * 512;
        const unsigned short* wk = wqkv + (size_t)(512 +  h*64 + dt*16 + l15) * 512;
        #pragma unroll 4
        for (int ks = 0; ks < 16; ++ks) {
            const int col = ks*32 + quad*8;
            short8 a0 = *(const short8*)(wq + col);
            short8 a1 = *(const short8*)(wk + col);
            #pragma unroll
            for (int nt = 0; nt < 4; ++nt) {
                short8 b = *(const short8*)(&xs[nt*16 + l15][col]);
                aq[nt] = __builtin_amdgcn_mfma_f32_16x16x32_bf16(a0, b, aq[nt], 0,0,0);
                ak[nt] = __builtin_amdgcn_mfma_f32_16x16x32_bf16(a1, b, ak[nt], 0,0,0);
            }
        }
        float bq[4], bk2[4];
        #pragma unroll
        for (int r = 0; r < 4; ++r) {
            bq[r]  = bqkv[       h*64 + dt*16 + quad*4 + r];
            bk2[r] = bqkv[512 +  h*64 + dt*16 + quad*4 + r];
        }
        const bool take = ((quad >> 1) == (dt & 1));
        const int  ks2  = dt >> 1;
        #pragma unroll
        for (int nt = 0; nt < 4; ++nt) {
            unsigned q01 = pack2(aq[nt][0]+bq[0],  aq[nt][1]+bq[1]);
            unsigned q23 = pack2(aq[nt][2]+bq[2],  aq[nt][3]+bq[3]);
            unsigned k01 = pack2(ak[nt][0]+bk2[0], ak[nt][1]+bk2[1]);
            unsigned k23 = pack2(ak[nt][2]+bk2[2], ak[nt][3]+bk2[3]);
            #pragma unroll
            for (int j = 0; j < 4; ++j) {
                int srcl = ((quad & 1)*2 + (j >> 1))*16 + l15;
                unsigned tq = (unsigned)__shfl((int)((j & 1) ? q23 : q01), srcl);
                unsigned tk = (unsigned)__shfl((int)((j & 1) ? k23 : k01), srcl);
                if (take) { qA[nt][ks2].u[j] = tq; kB[nt][ks2].u[j] = tk; }
            }
        }
    }

    // ======== scores (TRANSPOSED) + softmax + P^T->pA, per n-tile a ========
    U8 pA[4][2];   // A-frag: lane holds P[n=a*16+l15][m=ks2*32+quad*8+j]
    #pragma unroll
    for (int a = 0; a < 4; ++a) {
        f32x4 sc[4];
        #pragma unroll
        for (int b = 0; b < 4; ++b) sc[b] = (f32x4){0.f,0.f,0.f,0.f};
        #pragma unroll
        for (int ks2 = 0; ks2 < 2; ++ks2)
            #pragma unroll
            for (int b = 0; b < 4; ++b)
                sc[b] = __builtin_amdgcn_mfma_f32_16x16x32_bf16(
                            kB[b][ks2].s, qA[a][ks2].s, sc[b], 0,0,0);
        float m0 = -1e30f;
        #pragma unroll
        for (int b = 0; b < 4; ++b)
            #pragma unroll
            for (int r = 0; r < 4; ++r) { sc[b][r] *= 0.125f; m0 = fmaxf(m0, sc[b][r]); }
        m0 = fmaxf(m0, __shfl_xor(m0, 16));
        m0 = fmaxf(m0, __shfl_xor(m0, 32));
        float ssum = 0.f;
        #pragma unroll
        for (int b = 0; b < 4; ++b)
            #pragma unroll
            for (int r = 0; r < 4; ++r) { float e = __expf(sc[b][r] - m0); sc[b][r] = e; ssum += e; }
        ssum += __shfl_xor(ssum, 16);
        ssum += __shfl_xor(ssum, 32);
        float inv = 1.0f / ssum;
        unsigned pp[4][2];
        #pragma unroll
        for (int b = 0; b < 4; ++b) {
            pp[b][0] = pack2(sc[b][0]*inv, sc[b][1]*inv);
            pp[b][1] = pack2(sc[b][2]*inv, sc[b][3]*inv);
        }
        #pragma unroll
        for (int ks2 = 0; ks2 < 2; ++ks2)
            #pragma unroll
            for (int j = 0; j < 4; ++j) {
                int srcl = ((quad & 1)*2 + (j >> 1))*16 + l15;
                unsigned t0 = (unsigned)__shfl((int)pp[ks2*2    ][j & 1], srcl);
                unsigned t1 = (unsigned)__shfl((int)pp[ks2*2 + 1][j & 1], srcl);
                pA[a][ks2].u[j] = (quad >> 1) ? t1 : t0;
            }
    }

    // ======== pass-B: v-projection -> vB frags; y = V.u accumulated ========
    // vB: lane holds V[m=ks2*32+quad*8+j][d=dt*16+l15] (+bias)
    U8 vB[4][2];
    float ym[2][8];   // y[m] partials for this lane's m-slots
    #pragma unroll
    for (int ks2 = 0; ks2 < 2; ++ks2)
        #pragma unroll
        for (int m = 0; m < 8; ++m) ym[ks2][m] = 0.f;
    #pragma unroll
    for (int dt = 0; dt < 4; ++dt) {
        f32x4 av[4];
        #pragma unroll
        for (int mt = 0; mt < 4; ++mt) av[mt] = (f32x4){0.f,0.f,0.f,0.f};
        const unsigned short* wv = wqkv + (size_t)(1024 + h*64 + dt*16 + l15) * 512;
        #pragma unroll 4
        for (int ks = 0; ks < 16; ++ks) {
            const int col = ks*32 + quad*8;
            short8 a2 = *(const short8*)(wv + col);
            #pragma unroll
            for (int mt = 0; mt < 4; ++mt) {
                short8 b = *(const short8*)(&xs[mt*16 + l15][col]);
                av[mt] = __builtin_amdgcn_mfma_f32_16x16x32_bf16(b, a2, av[mt], 0,0,0);
            }
        }
        const float bv = bqkv[1024 + h*64 + dt*16 + l15];   // bias by d = lane
        unsigned vpk[4][2];
        #pragma unroll
        for (int mt = 0; mt < 4; ++mt) {
            vpk[mt][0] = pack2(av[mt][0]+bv, av[mt][1]+bv);
            vpk[mt][1] = pack2(av[mt][2]+bv, av[mt][3]+bv);
        }
        #pragma unroll
        for (int ks2 = 0; ks2 < 2; ++ks2)
            #pragma unroll
            for (int j = 0; j < 4; ++j) {
                int srcl = ((quad & 1)*2 + (j >> 1))*16 + l15;
                unsigned t0 = (unsigned)__shfl((int)vpk[ks2*2    ][j & 1], srcl);
                unsigned t1 = (unsigned)__shfl((int)vpk[ks2*2 + 1][j & 1], srcl);
                vB[dt][ks2].u[j] = (quad >> 1) ? t1 : t0;
            }
        const float ulv = u[h*64 + dt*16 + l15];
        #pragma unroll
        for (int ks2 = 0; ks2 < 2; ++ks2)
            #pragma unroll
            for (int j = 0; j < 4; ++j) {
                unsigned vv = vB[dt][ks2].u[j];
                ym[ks2][2*j]   += blo(vv) * ulv;
                ym[ks2][2*j+1] += bhi(vv) * ulv;
            }
    }
    // reduce y over l15 (d-dim): every lane then holds y[m] for its m-slots
    #pragma unroll
    for (int ks2 = 0; ks2 < 2; ++ks2)
        #pragma unroll
        for (int m = 0; m < 8; ++m) {
            float v = ym[ks2][m];
            v += __shfl_xor(v, 1); v += __shfl_xor(v, 2);
            v += __shfl_xor(v, 4); v += __shfl_xor(v, 8);
            ym[ks2][m] = v;
        }

    // ======== logit[n] = P.y  (reduce over quads' m-slots) ========
    #pragma unroll
    for (int a = 0; a < 4; ++a) {
        float lg = 0.f;
        #pragma unroll
        for (int ks2 = 0; ks2 < 2; ++ks2)
            #pragma unroll
            for (int j = 0; j < 4; ++j) {
                unsigned pv = pA[a][ks2].u[j];
                lg += blo(pv) * ym[ks2][2*j] + bhi(pv) * ym[ks2][2*j+1];
            }
        lg += __shfl_xor(lg, 16);
        lg += __shfl_xor(lg, 32);
        if (quad == 0) logitp[w][a*16 + l15] = lg;
    }
    __syncthreads();

    if (tid < 64) {
        float lg = c0[0];
        #pragma unroll
        for (int ww = 0; ww < 8; ++ww) lg += logitp[ww][tid];
        float gt = 1.0f / (1.0f + __expf(-lg));
        gatev[tid] = gt;
        float s = gt;
        s += __shfl_xor(s, 1);  s += __shfl_xor(s, 2);  s += __shfl_xor(s, 4);
        s += __shfl_xor(s, 8);  s += __shfl_xor(s, 16); s += __shfl_xor(s, 32);
        if (tid == 0) sgs = s;
    }
    __syncthreads();

    // ======== t = P^T.gate ; wctx[d] = V^T.t -> LDS overlay on xs ========
    float* wctxs = (float*)&xs[0][0];   // 512 f32 (xs dead for ALL waves)
    {
        float gl[4];
        #pragma unroll
        for (int a = 0; a < 4; ++a) gl[a] = gatev[a*16 + l15];
        float tm[2][8];
        #pragma unroll
        for (int ks2 = 0; ks2 < 2; ++ks2)
            #pragma unroll
            for (int j = 0; j < 4; ++j) {
                float t0 = 0.f, t1 = 0.f;
                #pragma unroll
                for (int a = 0; a < 4; ++a) {
                    unsigned pv = pA[a][ks2].u[j];
                    t0 += blo(pv) * gl[a];
                    t1 += bhi(pv) * gl[a];
                }
                tm[ks2][2*j] = t0; tm[ks2][2*j+1] = t1;
            }
        #pragma unroll
        for (int ks2 = 0; ks2 < 2; ++ks2)
            #pragma unroll
            for (int m = 0; m < 8; ++m) {
                float v = tm[ks2][m];
                v += __shfl_xor(v, 1); v += __shfl_xor(v, 2);
                v += __shfl_xor(v, 4); v += __shfl_xor(v, 8);
                tm[ks2][m] = v;
            }
        #pragma unroll
        for (int dt = 0; dt < 4; ++dt) {
            float s = 0.f;
            #pragma unroll
            for (int ks2 = 0; ks2 < 2; ++ks2)
                #pragma unroll
                for (int j = 0; j < 4; ++j) {
                    unsigned vv = vB[dt][ks2].u[j];
                    s += blo(vv) * tm[ks2][2*j] + bhi(vv) * tm[ks2][2*j+1];
                }
            s += __shfl_xor(s, 16);
            s += __shfl_xor(s, 32);
            if (quad == 0) wctxs[h*64 + dt*16 + l15] = s;
        }
    }
    __syncthreads();

    // ======== fused out-projection GEMV: out[g][e] = wctx.Wo[e,:] + sgs*bo[e] ========
    {
        const unsigned short* wr = wo_bf + (size_t)tid * 512;   // row e = tid
        float acc = 0.f;
        #pragma unroll 8
        for (int i = 0; i < 64; ++i) {
            uint4  w4 = *(const uint4*)(wr + i*8);
            float4 ca = *(const float4*)(wctxs + i*8);
            float4 cb = *(const float4*)(wctxs + i*8 + 4);
            acc += blo(w4.x)*ca.x + bhi(w4.x)*ca.y + blo(w4.y)*ca.z + bhi(w4.y)*ca.w
                 + blo(w4.z)*cb.x + bhi(w4.z)*cb.y + blo(w4.w)*cb.z + bhi(w4.w)*cb.w;
        }
        out[(size_t)g*512 + tid] = acc + sgs * bo[tid];
    }
}

extern "C" void kernel_launch(void* const* d_in, const int* in_sizes, int n_in,
                              void* d_out, int out_size, void* d_ws, size_t ws_size,
                              hipStream_t stream) {
    const float* x    = (const float*)d_in[0];
    // d_in[1] = batch (int64) — unused: graphs are equal-sized (64 nodes)
    const float* wqkv = (const float*)d_in[2];
    const float* bqkv = (const float*)d_in[3];
    const float* wo   = (const float*)d_in[4];
    const float* bo   = (const float*)d_in[5];
    const float* gw   = (const float*)d_in[6];
    const float* gb   = (const float*)d_in[7];
    float* out = (float*)d_out;

    char* ws = (char*)d_ws;
    unsigned short* wqkv_bf = (unsigned short*)(ws + WQKV_OFF);
    unsigned short* wo_bf   = (unsigned short*)(ws + WO_OFF);
    float*          upart   = (float*)(ws + UPART_OFF);
    float*          u_ws    = (float*)(ws + U_OFF);
    float*          c0_ws   = (float*)(ws + C0_OFF);

    const int total = in_sizes[0] / D_;  // 65536 nodes
    const int G     = total / 64;        // 1024 graphs

    hipLaunchKernelGGL(convert_and_u, dim3(1040), dim3(256), 0, stream,
                       wqkv, wo, gw, wqkv_bf, upart);
    hipLaunchKernelGGL(finalize_u,    dim3(1),    dim3(256), 0, stream,
                       upart, bo, gw, gb, u_ws, c0_ws);
    hipLaunchKernelGGL(attn_full_kernel, dim3(G), dim3(512), 0, stream,
                       x, wqkv_bf, bqkv, wo_bf, bo, u_ws, c0_ws, out);
}

// Round 10
// 487.145 us; speedup vs baseline: 1.0080x; 1.0080x over previous
//
#include <hip/hip_runtime.h>
#include <stdint.h>

// AttentionReadout: G=1024 x N=64, D=512, H=8, hd=64. fp32 I/O, bf16 MFMA.
// v10 = v9 with ONE change: __launch_bounds__(512, 2).
// ROUNDS 7-9 LESSON: hipcc treats the 2nd launch_bounds arg as min BLOCKS/CU
// (CUDA semantics): (512,4) -> 4 blocks x 8 waves = 8 waves/SIMD -> 64-VGPR
// cap -> 80-300 MB spill traffic (VGPR_Count pinned at 64 three rounds in a
// row). (512,2) -> 16 waves/CU -> 128-VGPR cap, which v9's ~100-reg live set
// fits. v9 algorithm: ctx = P@V never materialized (logit = P.(V.u),
// wctx = V^T.(P^T.gate)); P/V live only as MFMA frags; fused out-proj GEMV.

typedef __attribute__((ext_vector_type(8))) short short8;   // 8 bf16
typedef __attribute__((ext_vector_type(4))) float f32x4;    // MFMA C/D frag

#define D_ 512

// ---- ws layout (bytes) ----
#define WQKV_OFF   0u          // 1536*512 bf16 = 1572864
#define WO_OFF     1572864u    // 512*512 bf16  = 524288
#define UPART_OFF  2097152u    // 16*512 f32    = 32768
#define U_OFF      2129920u    // 512 f32       = 2048
#define C0_OFF     2131968u    // 64

__device__ __forceinline__ unsigned short f2bf(float f) {
    union { float f; unsigned int u; } t; t.f = f;
    unsigned int u = t.u;
    return (unsigned short)((u + 0x7FFFu + ((u >> 16) & 1u)) >> 16);  // RNE
}
__device__ __forceinline__ unsigned pack2(float a, float b) {
    return (unsigned)f2bf(a) | ((unsigned)f2bf(b) << 16);
}
__device__ __forceinline__ float blo(unsigned v) {
    union { unsigned u; float f; } t; t.u = v << 16; return t.f;
}
__device__ __forceinline__ float bhi(unsigned v) {
    union { unsigned u; float f; } t; t.u = v & 0xFFFF0000u; return t.f;
}

// ---- pre-pass 1 (merged): blocks 0..1023 convert weights; 1024..1039 u-partials ----
__global__ __launch_bounds__(256)
void convert_and_u(const float* __restrict__ wqkv, const float* __restrict__ wo,
                   const float* __restrict__ gw,
                   unsigned short* __restrict__ wbf, float* __restrict__ upart) {
    const int b = blockIdx.x;
    const int t = threadIdx.x;
    if (b < 1024) {
        const int i4 = b * 256 + t;          // 262144 float4 total
        float4 v;
        if (i4 < 196608) v = *(const float4*)(wqkv + (size_t)i4 * 4);
        else             v = *(const float4*)(wo   + (size_t)(i4 - 196608) * 4);
        uint2 p; p.x = pack2(v.x, v.y); p.y = pack2(v.z, v.w);
        *(uint2*)(wbf + (size_t)i4 * 4) = p;
    } else {
        const int bb = b - 1024;             // 16 blocks
        float a0 = 0.f, a1 = 0.f;
        #pragma unroll 4
        for (int e = bb * 32; e < bb * 32 + 32; ++e) {
            const float ge = gw[e];
            a0 += wo[(size_t)e * 512 + t]       * ge;
            a1 += wo[(size_t)e * 512 + t + 256] * ge;
        }
        upart[bb * 512 + t] = a0; upart[bb * 512 + t + 256] = a1;
    }
}

// ---- pre-pass 2: u = sum partials; c0 = bo.gw + gb ----
__global__ __launch_bounds__(256)
void finalize_u(const float* __restrict__ upart, const float* __restrict__ bo,
                const float* __restrict__ gw, const float* __restrict__ gb,
                float* __restrict__ u, float* __restrict__ c0) {
    const int t = threadIdx.x;
    float s0 = 0.f, s1 = 0.f;
    #pragma unroll
    for (int b = 0; b < 16; ++b) { s0 += upart[b*512 + t]; s1 += upart[b*512 + t + 256]; }
    u[t] = s0; u[t + 256] = s1;
    __shared__ float rb[256];
    rb[t] = bo[t] * gw[t] + bo[t + 256] * gw[t + 256];
    __syncthreads();
    for (int s = 128; s > 0; s >>= 1) { if (t < s) rb[t] += rb[t + s]; __syncthreads(); }
    if (t == 0) c0[0] = rb[0] + gb[0];
}

union U8 { unsigned u[4]; short8 s; };

// ---- main: per-graph, wave-per-head, no ctx, fused out-proj ----
__global__ __launch_bounds__(512, 2)
void attn_full_kernel(const float* __restrict__ x,             // [65536,512] f32
                      const unsigned short* __restrict__ wqkv, // [1536,512] bf16
                      const float* __restrict__ bqkv,          // [1536] f32
                      const unsigned short* __restrict__ wo_bf,// [512,512] bf16
                      const float* __restrict__ bo,            // [512] f32
                      const float* __restrict__ u,             // [512] f32
                      const float* __restrict__ c0,            // [1] f32
                      float* __restrict__ out)                 // [1024,512] f32
{
    __shared__ unsigned short xs[64][520];     // 66560 B; epilogue overlays wctx
    __shared__ float logitp[8][64];            // 2048 B
    __shared__ float gatev[64];                // 256 B
    __shared__ float sgs;                      // 4 B
    // total ~68.9 KB -> 2 blocks/CU (LDS), 16 waves/CU (4/SIMD)

    const int g    = blockIdx.x;
    const int tid  = threadIdx.x;
    const int w    = tid >> 6;      // wave = head
    const int lane = tid & 63;
    const int l15  = lane & 15;
    const int quad = lane >> 4;

    // ---- stage x once: fp32 -> bf16 LDS ----
    #pragma unroll
    for (int i = 0; i < 16; ++i) {
        int idx = tid + i * 512;
        int row = idx >> 7;
        int c4  = idx & 127;
        float4 v = *(const float4*)(x + ((size_t)(g*64 + row))*512 + c4*4);
        uint2 p; p.x = pack2(v.x, v.y); p.y = pack2(v.z, v.w);
        *(uint2*)(&xs[row][c4*4]) = p;
    }
    __syncthreads();

    const int h = w;

    // ======== pass-A: q,k (K=512) -> score frags in-register ========
    U8 qA[4][2], kB[4][2];   // [n-strip][ks2]
    #pragma unroll
    for (int dt = 0; dt < 4; ++dt) {
        f32x4 aq[4], ak[4];
        #pragma unroll
        for (int nt = 0; nt < 4; ++nt) {
            aq[nt] = (f32x4){0.f,0.f,0.f,0.f};
            ak[nt] = (f32x4){0.f,0.f,0.f,0.f};
        }
        const unsigned short* wq = wqkv + (size_t)(       h*64 + dt*16 + l15) * 512;
        const unsigned short* wk = wqkv + (size_t)(512 +  h*64 + dt*16 + l15) * 512;
        #pragma unroll 4
        for (int ks = 0; ks < 16; ++ks) {
            const int col = ks*32 + quad*8;
            short8 a0 = *(const short8*)(wq + col);
            short8 a1 = *(const short8*)(wk + col);
            #pragma unroll
            for (int nt = 0; nt < 4; ++nt) {
                short8 b = *(const short8*)(&xs[nt*16 + l15][col]);
                aq[nt] = __builtin_amdgcn_mfma_f32_16x16x32_bf16(a0, b, aq[nt], 0,0,0);
                ak[nt] = __builtin_amdgcn_mfma_f32_16x16x32_bf16(a1, b, ak[nt], 0,0,0);
            }
        }
        float bq[4], bk2[4];
        #pragma unroll
        for (int r = 0; r < 4; ++r) {
            bq[r]  = bqkv[       h*64 + dt*16 + quad*4 + r];
            bk2[r] = bqkv[512 +  h*64 + dt*16 + quad*4 + r];
        }
        const bool take = ((quad >> 1) == (dt & 1));
        const int  ks2  = dt >> 1;
        #pragma unroll
        for (int nt = 0; nt < 4; ++nt) {
            unsigned q01 = pack2(aq[nt][0]+bq[0],  aq[nt][1]+bq[1]);
            unsigned q23 = pack2(aq[nt][2]+bq[2],  aq[nt][3]+bq[3]);
            unsigned k01 = pack2(ak[nt][0]+bk2[0], ak[nt][1]+bk2[1]);
            unsigned k23 = pack2(ak[nt][2]+bk2[2], ak[nt][3]+bk2[3]);
            #pragma unroll
            for (int j = 0; j < 4; ++j) {
                int srcl = ((quad & 1)*2 + (j >> 1))*16 + l15;
                unsigned tq = (unsigned)__shfl((int)((j & 1) ? q23 : q01), srcl);
                unsigned tk = (unsigned)__shfl((int)((j & 1) ? k23 : k01), srcl);
                if (take) { qA[nt][ks2].u[j] = tq; kB[nt][ks2].u[j] = tk; }
            }
        }
    }

    // ======== scores (TRANSPOSED) + softmax + P^T->pA, per n-tile a ========
    U8 pA[4][2];   // A-frag: lane holds P[n=a*16+l15][m=ks2*32+quad*8+j]
    #pragma unroll
    for (int a = 0; a < 4; ++a) {
        f32x4 sc[4];
        #pragma unroll
        for (int b = 0; b < 4; ++b) sc[b] = (f32x4){0.f,0.f,0.f,0.f};
        #pragma unroll
        for (int ks2 = 0; ks2 < 2; ++ks2)
            #pragma unroll
            for (int b = 0; b < 4; ++b)
                sc[b] = __builtin_amdgcn_mfma_f32_16x16x32_bf16(
                            kB[b][ks2].s, qA[a][ks2].s, sc[b], 0,0,0);
        float m0 = -1e30f;
        #pragma unroll
        for (int b = 0; b < 4; ++b)
            #pragma unroll
            for (int r = 0; r < 4; ++r) { sc[b][r] *= 0.125f; m0 = fmaxf(m0, sc[b][r]); }
        m0 = fmaxf(m0, __shfl_xor(m0, 16));
        m0 = fmaxf(m0, __shfl_xor(m0, 32));
        float ssum = 0.f;
        #pragma unroll
        for (int b = 0; b < 4; ++b)
            #pragma unroll
            for (int r = 0; r < 4; ++r) { float e = __expf(sc[b][r] - m0); sc[b][r] = e; ssum += e; }
        ssum += __shfl_xor(ssum, 16);
        ssum += __shfl_xor(ssum, 32);
        float inv = 1.0f / ssum;
        unsigned pp[4][2];
        #pragma unroll
        for (int b = 0; b < 4; ++b) {
            pp[b][0] = pack2(sc[b][0]*inv, sc[b][1]*inv);
            pp[b][1] = pack2(sc[b][2]*inv, sc[b][3]*inv);
        }
        #pragma unroll
        for (int ks2 = 0; ks2 < 2; ++ks2)
            #pragma unroll
            for (int j = 0; j < 4; ++j) {
                int srcl = ((quad & 1)*2 + (j >> 1))*16 + l15;
                unsigned t0 = (unsigned)__shfl((int)pp[ks2*2    ][j & 1], srcl);
                unsigned t1 = (unsigned)__shfl((int)pp[ks2*2 + 1][j & 1], srcl);
                pA[a][ks2].u[j] = (quad >> 1) ? t1 : t0;
            }
    }

    // ======== pass-B: v-projection -> vB frags; y = V.u accumulated ========
    // vB: lane holds V[m=ks2*32+quad*8+j][d=dt*16+l15] (+bias)
    U8 vB[4][2];
    float ym[2][8];   // y[m] partials for this lane's m-slots
    #pragma unroll
    for (int ks2 = 0; ks2 < 2; ++ks2)
        #pragma unroll
        for (int m = 0; m < 8; ++m) ym[ks2][m] = 0.f;
    #pragma unroll
    for (int dt = 0; dt < 4; ++dt) {
        f32x4 av[4];
        #pragma unroll
        for (int mt = 0; mt < 4; ++mt) av[mt] = (f32x4){0.f,0.f,0.f,0.f};
        const unsigned short* wv = wqkv + (size_t)(1024 + h*64 + dt*16 + l15) * 512;
        #pragma unroll 4
        for (int ks = 0; ks < 16; ++ks) {
            const int col = ks*32 + quad*8;
            short8 a2 = *(const short8*)(wv + col);
            #pragma unroll
            for (int mt = 0; mt < 4; ++mt) {
                short8 b = *(const short8*)(&xs[mt*16 + l15][col]);
                av[mt] = __builtin_amdgcn_mfma_f32_16x16x32_bf16(b, a2, av[mt], 0,0,0);
            }
        }
        const float bv = bqkv[1024 + h*64 + dt*16 + l15];   // bias by d = lane
        unsigned vpk[4][2];
        #pragma unroll
        for (int mt = 0; mt < 4; ++mt) {
            vpk[mt][0] = pack2(av[mt][0]+bv, av[mt][1]+bv);
            vpk[mt][1] = pack2(av[mt][2]+bv, av[mt][3]+bv);
        }
        #pragma unroll
        for (int ks2 = 0; ks2 < 2; ++ks2)
            #pragma unroll
            for (int j = 0; j < 4; ++j) {
                int srcl = ((quad & 1)*2 + (j >> 1))*16 + l15;
                unsigned t0 = (unsigned)__shfl((int)vpk[ks2*2    ][j & 1], srcl);
                unsigned t1 = (unsigned)__shfl((int)vpk[ks2*2 + 1][j & 1], srcl);
                vB[dt][ks2].u[j] = (quad >> 1) ? t1 : t0;
            }
        const float ulv = u[h*64 + dt*16 + l15];
        #pragma unroll
        for (int ks2 = 0; ks2 < 2; ++ks2)
            #pragma unroll
            for (int j = 0; j < 4; ++j) {
                unsigned vv = vB[dt][ks2].u[j];
                ym[ks2][2*j]   += blo(vv) * ulv;
                ym[ks2][2*j+1] += bhi(vv) * ulv;
            }
    }
    // reduce y over l15 (d-dim): every lane then holds y[m] for its m-slots
    #pragma unroll
    for (int ks2 = 0; ks2 < 2; ++ks2)
        #pragma unroll
        for (int m = 0; m < 8; ++m) {
            float v = ym[ks2][m];
            v += __shfl_xor(v, 1); v += __shfl_xor(v, 2);
            v += __shfl_xor(v, 4); v += __shfl_xor(v, 8);
            ym[ks2][m] = v;
        }

    // ======== logit[n] = P.y  (reduce over quads' m-slots) ========
    #pragma unroll
    for (int a = 0; a < 4; ++a) {
        float lg = 0.f;
        #pragma unroll
        for (int ks2 = 0; ks2 < 2; ++ks2)
            #pragma unroll
            for (int j = 0; j < 4; ++j) {
                unsigned pv = pA[a][ks2].u[j];
                lg += blo(pv) * ym[ks2][2*j] + bhi(pv) * ym[ks2][2*j+1];
            }
        lg += __shfl_xor(lg, 16);
        lg += __shfl_xor(lg, 32);
        if (quad == 0) logitp[w][a*16 + l15] = lg;
    }
    __syncthreads();

    if (tid < 64) {
        float lg = c0[0];
        #pragma unroll
        for (int ww = 0; ww < 8; ++ww) lg += logitp[ww][tid];
        float gt = 1.0f / (1.0f + __expf(-lg));
        gatev[tid] = gt;
        float s = gt;
        s += __shfl_xor(s, 1);  s += __shfl_xor(s, 2);  s += __shfl_xor(s, 4);
        s += __shfl_xor(s, 8);  s += __shfl_xor(s, 16); s += __shfl_xor(s, 32);
        if (tid == 0) sgs = s;
    }
    __syncthreads();

    // ======== t = P^T.gate ; wctx[d] = V^T.t -> LDS overlay on xs ========
    float* wctxs = (float*)&xs[0][0];   // 512 f32 (xs dead for ALL waves)
    {
        float gl[4];
        #pragma unroll
        for (int a = 0; a < 4; ++a) gl[a] = gatev[a*16 + l15];
        float tm[2][8];
        #pragma unroll
        for (int ks2 = 0; ks2 < 2; ++ks2)
            #pragma unroll
            for (int j = 0; j < 4; ++j) {
                float t0 = 0.f, t1 = 0.f;
                #pragma unroll
                for (int a = 0; a < 4; ++a) {
                    unsigned pv = pA[a][ks2].u[j];
                    t0 += blo(pv) * gl[a];
                    t1 += bhi(pv) * gl[a];
                }
                tm[ks2][2*j] = t0; tm[ks2][2*j+1] = t1;
            }
        #pragma unroll
        for (int ks2 = 0; ks2 < 2; ++ks2)
            #pragma unroll
            for (int m = 0; m < 8; ++m) {
                float v = tm[ks2][m];
                v += __shfl_xor(v, 1); v += __shfl_xor(v, 2);
                v += __shfl_xor(v, 4); v += __shfl_xor(v, 8);
                tm[ks2][m] = v;
            }
        #pragma unroll
        for (int dt = 0; dt < 4; ++dt) {
            float s = 0.f;
            #pragma unroll
            for (int ks2 = 0; ks2 < 2; ++ks2)
                #pragma unroll
                for (int j = 0; j < 4; ++j) {
                    unsigned vv = vB[dt][ks2].u[j];
                    s += blo(vv) * tm[ks2][2*j] + bhi(vv) * tm[ks2][2*j+1];
                }
            s += __shfl_xor(s, 16);
            s += __shfl_xor(s, 32);
            if (quad == 0) wctxs[h*64 + dt*16 + l15] = s;
        }
    }
    __syncthreads();

    // ======== fused out-projection GEMV: out[g][e] = wctx.Wo[e,:] + sgs*bo[e] ========
    {
        const unsigned short* wr = wo_bf + (size_t)tid * 512;   // row e = tid
        float acc = 0.f;
        #pragma unroll 8
        for (int i = 0; i < 64; ++i) {
            uint4  w4 = *(const uint4*)(wr + i*8);
            float4 ca = *(const float4*)(wctxs + i*8);
            float4 cb = *(const float4*)(wctxs + i*8 + 4);
            acc += blo(w4.x)*ca.x + bhi(w4.x)*ca.y + blo(w4.y)*ca.z + bhi(w4.y)*ca.w
                 + blo(w4.z)*cb.x + bhi(w4.z)*cb.y + blo(w4.w)*cb.z + bhi(w4.w)*cb.w;
        }
        out[(size_t)g*512 + tid] = acc + sgs * bo[tid];
    }
}

extern "C" void kernel_launch(void* const* d_in, const int* in_sizes, int n_in,
                              void* d_out, int out_size, void* d_ws, size_t ws_size,
                              hipStream_t stream) {
    const float* x    = (const float*)d_in[0];
    // d_in[1] = batch (int64) — unused: graphs are equal-sized (64 nodes)
    const float* wqkv = (const float*)d_in[2];
    const float* bqkv = (const float*)d_in[3];
    const float* wo   = (const float*)d_in[4];
    const float* bo   = (const float*)d_in[5];
    const float* gw   = (const float*)d_in[6];
    const float* gb   = (const float*)d_in[7];
    float* out = (float*)d_out;

    char* ws = (char*)d_ws;
    unsigned short* wqkv_bf = (unsigned short*)(ws + WQKV_OFF);
    unsigned short* wo_bf   = (unsigned short*)(ws + WO_OFF);
    float*          upart   = (float*)(ws + UPART_OFF);
    float*          u_ws    = (float*)(ws + U_OFF);
    float*          c0_ws   = (float*)(ws + C0_OFF);

    const int total = in_sizes[0] / D_;  // 65536 nodes
    const int G     = total / 64;        // 1024 graphs

    hipLaunchKernelGGL(convert_and_u, dim3(1040), dim3(256), 0, stream,
                       wqkv, wo, gw, wqkv_bf, upart);
    hipLaunchKernelGGL(finalize_u,    dim3(1),    dim3(256), 0, stream,
                       upart, bo, gw, gb, u_ws, c0_ws);
    hipLaunchKernelGGL(attn_full_kernel, dim3(G), dim3(512), 0, stream,
                       x, wqkv_bf, bqkv, wo_bf, bo, u_ws, c0_ws, out);
}

// Round 11
// 464.648 us; speedup vs baseline: 1.0569x; 1.0484x over previous
//
#include <hip/hip_runtime.h>
#include <hip/hip_bf16.h>
#include <stdint.h>

// AttentionReadout: G=1024 x N=64, D=512, H=8, hd=64. fp32 I/O, bf16 MFMA.
// v11 = v10 (ctx-free linear-algebra form) with:
//  - 2 launches (aux merges convert+u-partials+c0; attn sums u-partials inline)
//  - packed bf16 cvt (__float22bfloat162_rn -> v_cvt_pk_bf16_f32)
//  - MFMA-based out-proj GEMV epilogue (replaces ~1500 VALU instr/thread)
//  - LDS shrunk to exactly 65536 B: unpadded xs[64][512] with XOR-swizzled
//    16B chunks (2-way bank conflicts = free); logitp/gatev/sgs/wctx all
//    overlaid onto dead xs regions (occupancy probe: is >64KB LDS the
//    1-block/CU limiter?)
// Known: launch_bounds 2nd arg = min BLOCKS/CU on hipcc; (512,2) -> 128-reg cap.

typedef __attribute__((ext_vector_type(8))) short short8;   // 8 bf16
typedef __attribute__((ext_vector_type(4))) float f32x4;    // MFMA C/D frag

#define D_ 512

// ---- ws layout (bytes) ----
#define WQKV_OFF   0u          // 1536*512 bf16 = 1572864
#define WO_OFF     1572864u    // 512*512 bf16  = 524288
#define UPART_OFF  2097152u    // 16*512 f32    = 32768
#define C0_OFF     2131968u    // 64

__device__ __forceinline__ unsigned pack2(float a, float b) {
    __hip_bfloat162 h = __float22bfloat162_rn(make_float2(a, b));  // RNE packed
    unsigned r; __builtin_memcpy(&r, &h, 4); return r;
}
__device__ __forceinline__ float blo(unsigned v) {
    union { unsigned u; float f; } t; t.u = v << 16; return t.f;
}
__device__ __forceinline__ float bhi(unsigned v) {
    union { unsigned u; float f; } t; t.u = v & 0xFFFF0000u; return t.f;
}

// ---- aux (single launch): convert weights; u-partials; c0 ----
__global__ __launch_bounds__(256)
void aux_kernel(const float* __restrict__ wqkv, const float* __restrict__ wo,
                const float* __restrict__ gw, const float* __restrict__ bo,
                const float* __restrict__ gb,
                unsigned short* __restrict__ wbf, float* __restrict__ upart,
                float* __restrict__ c0) {
    __shared__ float rb[256];
    const int b = blockIdx.x;
    const int t = threadIdx.x;
    if (b < 1024) {
        const int i4 = b * 256 + t;          // 262144 float4 total
        float4 v;
        if (i4 < 196608) v = *(const float4*)(wqkv + (size_t)i4 * 4);
        else             v = *(const float4*)(wo   + (size_t)(i4 - 196608) * 4);
        uint2 p; p.x = pack2(v.x, v.y); p.y = pack2(v.z, v.w);
        *(uint2*)(wbf + (size_t)i4 * 4) = p;
    } else if (b < 1040) {
        const int bb = b - 1024;             // 16 u-partial blocks
        float a0 = 0.f, a1 = 0.f;
        #pragma unroll 4
        for (int e = bb * 32; e < bb * 32 + 32; ++e) {
            const float ge = gw[e];
            a0 += wo[(size_t)e * 512 + t]       * ge;
            a1 += wo[(size_t)e * 512 + t + 256] * ge;
        }
        upart[bb * 512 + t] = a0; upart[bb * 512 + t + 256] = a1;
    } else {
        rb[t] = bo[t] * gw[t] + bo[t + 256] * gw[t + 256];
        __syncthreads();
        for (int s = 128; s > 0; s >>= 1) { if (t < s) rb[t] += rb[t + s]; __syncthreads(); }
        if (t == 0) c0[0] = rb[0] + gb[0];
    }
}

union U8 { unsigned u[4]; short8 s; };

// ---- main: per-graph, wave-per-head, ctx-free, fused MFMA out-proj ----
__global__ __launch_bounds__(512, 2)
void attn_full_kernel(const float* __restrict__ x,             // [65536,512] f32
                      const unsigned short* __restrict__ wqkv, // [1536,512] bf16
                      const float* __restrict__ bqkv,          // [1536] f32
                      const unsigned short* __restrict__ wo_bf,// [512,512] bf16
                      const float* __restrict__ bo,            // [512] f32
                      const float* __restrict__ upart,         // [16,512] f32
                      const float* __restrict__ c0,            // [1] f32
                      float* __restrict__ out)                 // [1024,512] f32
{
    // exactly 64 KB LDS; xs is XOR-swizzled [64][512] bf16 (16B chunk ^= row&7)
    __shared__ unsigned short xs[64 * 512];
    float* wctxs  = (float*)xs;          // [0,512)    overlay (epilogue)
    float* logitp = (float*)xs + 512;    // [512,1024) overlay (post pass-B)
    float* gatev  = (float*)xs + 1024;   // [1024,1088)
    float* sgsp   = (float*)xs + 1088;

    const int g    = blockIdx.x;
    const int tid  = threadIdx.x;
    const int w    = tid >> 6;      // wave = head
    const int lane = tid & 63;
    const int l15  = lane & 15;
    const int quad = lane >> 4;
    const int q7   = l15 & 7;       // (row & 7) for row = nt*16 + l15

    // ---- stage x once: fp32 -> bf16 swizzled LDS ----
    #pragma unroll
    for (int i = 0; i < 16; ++i) {
        int idx  = tid + i * 512;         // 8192 float4
        int row  = idx >> 7;              // 128 float4 per row
        int c4   = idx & 127;
        int ch   = c4 >> 1;               // 16B chunk 0..63
        int half = c4 & 1;
        float4 v = *(const float4*)(x + ((size_t)(g*64 + row))*512 + c4*4);
        uint2 p; p.x = pack2(v.x, v.y); p.y = pack2(v.z, v.w);
        *(uint2*)(xs + row*512 + ((ch ^ (row & 7)) << 3) + (half << 2)) = p;
    }
    __syncthreads();

    const int h = w;

    // ======== pass-A: q,k (K=512) -> score frags in-register ========
    U8 qA[4][2], kB[4][2];   // [n-strip][ks2]
    #pragma unroll
    for (int dt = 0; dt < 4; ++dt) {
        f32x4 aq[4], ak[4];
        #pragma unroll
        for (int nt = 0; nt < 4; ++nt) {
            aq[nt] = (f32x4){0.f,0.f,0.f,0.f};
            ak[nt] = (f32x4){0.f,0.f,0.f,0.f};
        }
        const unsigned short* wq = wqkv + (size_t)(       h*64 + dt*16 + l15) * 512;
        const unsigned short* wk = wqkv + (size_t)(512 +  h*64 + dt*16 + l15) * 512;
        #pragma unroll 4
        for (int ks = 0; ks < 16; ++ks) {
            const int col = ks*32 + quad*8;
            short8 a0 = *(const short8*)(wq + col);
            short8 a1 = *(const short8*)(wk + col);
            #pragma unroll
            for (int nt = 0; nt < 4; ++nt) {
                short8 b = *(const short8*)(xs + (nt*16 + l15)*512 + (((ks*4 + quad) ^ q7) << 3));
                aq[nt] = __builtin_amdgcn_mfma_f32_16x16x32_bf16(a0, b, aq[nt], 0,0,0);
                ak[nt] = __builtin_amdgcn_mfma_f32_16x16x32_bf16(a1, b, ak[nt], 0,0,0);
            }
        }
        float bq[4], bk2[4];
        #pragma unroll
        for (int r = 0; r < 4; ++r) {
            bq[r]  = bqkv[       h*64 + dt*16 + quad*4 + r];
            bk2[r] = bqkv[512 +  h*64 + dt*16 + quad*4 + r];
        }
        const bool take = ((quad >> 1) == (dt & 1));
        const int  ks2  = dt >> 1;
        #pragma unroll
        for (int nt = 0; nt < 4; ++nt) {
            unsigned q01 = pack2(aq[nt][0]+bq[0],  aq[nt][1]+bq[1]);
            unsigned q23 = pack2(aq[nt][2]+bq[2],  aq[nt][3]+bq[3]);
            unsigned k01 = pack2(ak[nt][0]+bk2[0], ak[nt][1]+bk2[1]);
            unsigned k23 = pack2(ak[nt][2]+bk2[2], ak[nt][3]+bk2[3]);
            #pragma unroll
            for (int j = 0; j < 4; ++j) {
                int srcl = ((quad & 1)*2 + (j >> 1))*16 + l15;
                unsigned tq = (unsigned)__shfl((int)((j & 1) ? q23 : q01), srcl);
                unsigned tk = (unsigned)__shfl((int)((j & 1) ? k23 : k01), srcl);
                if (take) { qA[nt][ks2].u[j] = tq; kB[nt][ks2].u[j] = tk; }
            }
        }
    }

    // ======== scores (transposed) + softmax + P^T->pA, per n-tile a ========
    U8 pA[4][2];   // lane holds P[n=a*16+l15][m=ks2*32+quad*8+j]
    #pragma unroll
    for (int a = 0; a < 4; ++a) {
        f32x4 sc[4];
        #pragma unroll
        for (int b = 0; b < 4; ++b) sc[b] = (f32x4){0.f,0.f,0.f,0.f};
        #pragma unroll
        for (int ks2 = 0; ks2 < 2; ++ks2)
            #pragma unroll
            for (int b = 0; b < 4; ++b)
                sc[b] = __builtin_amdgcn_mfma_f32_16x16x32_bf16(
                            kB[b][ks2].s, qA[a][ks2].s, sc[b], 0,0,0);
        float m0 = -1e30f;
        #pragma unroll
        for (int b = 0; b < 4; ++b)
            #pragma unroll
            for (int r = 0; r < 4; ++r) { sc[b][r] *= 0.125f; m0 = fmaxf(m0, sc[b][r]); }
        m0 = fmaxf(m0, __shfl_xor(m0, 16));
        m0 = fmaxf(m0, __shfl_xor(m0, 32));
        float ssum = 0.f;
        #pragma unroll
        for (int b = 0; b < 4; ++b)
            #pragma unroll
            for (int r = 0; r < 4; ++r) { float e = __expf(sc[b][r] - m0); sc[b][r] = e; ssum += e; }
        ssum += __shfl_xor(ssum, 16);
        ssum += __shfl_xor(ssum, 32);
        float inv = 1.0f / ssum;
        unsigned pp[4][2];
        #pragma unroll
        for (int b = 0; b < 4; ++b) {
            pp[b][0] = pack2(sc[b][0]*inv, sc[b][1]*inv);
            pp[b][1] = pack2(sc[b][2]*inv, sc[b][3]*inv);
        }
        #pragma unroll
        for (int ks2 = 0; ks2 < 2; ++ks2)
            #pragma unroll
            for (int j = 0; j < 4; ++j) {
                int srcl = ((quad & 1)*2 + (j >> 1))*16 + l15;
                unsigned t0 = (unsigned)__shfl((int)pp[ks2*2    ][j & 1], srcl);
                unsigned t1 = (unsigned)__shfl((int)pp[ks2*2 + 1][j & 1], srcl);
                pA[a][ks2].u[j] = (quad >> 1) ? t1 : t0;
            }
    }

    // ---- u slice for this head (sum of 16 partials; finalize_u eliminated) ----
    float u4[4];
    #pragma unroll
    for (int dt = 0; dt < 4; ++dt) {
        float s = 0.f;
        #pragma unroll
        for (int bb = 0; bb < 16; ++bb) s += upart[bb*512 + h*64 + dt*16 + l15];
        u4[dt] = s;
    }

    // ======== pass-B: v-projection -> vB frags; y = V.u accumulated ========
    U8 vB[4][2];      // lane holds V[m=ks2*32+quad*8+j][d=dt*16+l15] (+bias)
    float ym[2][8];
    #pragma unroll
    for (int ks2 = 0; ks2 < 2; ++ks2)
        #pragma unroll
        for (int m = 0; m < 8; ++m) ym[ks2][m] = 0.f;
    #pragma unroll
    for (int dt = 0; dt < 4; ++dt) {
        f32x4 av[4];
        #pragma unroll
        for (int mt = 0; mt < 4; ++mt) av[mt] = (f32x4){0.f,0.f,0.f,0.f};
        const unsigned short* wv = wqkv + (size_t)(1024 + h*64 + dt*16 + l15) * 512;
        #pragma unroll 4
        for (int ks = 0; ks < 16; ++ks) {
            const int col = ks*32 + quad*8;
            short8 a2 = *(const short8*)(wv + col);
            #pragma unroll
            for (int mt = 0; mt < 4; ++mt) {
                short8 b = *(const short8*)(xs + (mt*16 + l15)*512 + (((ks*4 + quad) ^ q7) << 3));
                av[mt] = __builtin_amdgcn_mfma_f32_16x16x32_bf16(b, a2, av[mt], 0,0,0);
            }
        }
        const float bv = bqkv[1024 + h*64 + dt*16 + l15];   // bias by d = lane
        unsigned vpk[4][2];
        #pragma unroll
        for (int mt = 0; mt < 4; ++mt) {
            vpk[mt][0] = pack2(av[mt][0]+bv, av[mt][1]+bv);
            vpk[mt][1] = pack2(av[mt][2]+bv, av[mt][3]+bv);
        }
        #pragma unroll
        for (int ks2 = 0; ks2 < 2; ++ks2)
            #pragma unroll
            for (int j = 0; j < 4; ++j) {
                int srcl = ((quad & 1)*2 + (j >> 1))*16 + l15;
                unsigned t0 = (unsigned)__shfl((int)vpk[ks2*2    ][j & 1], srcl);
                unsigned t1 = (unsigned)__shfl((int)vpk[ks2*2 + 1][j & 1], srcl);
                vB[dt][ks2].u[j] = (quad >> 1) ? t1 : t0;
            }
        const float ulv = u4[dt];
        #pragma unroll
        for (int ks2 = 0; ks2 < 2; ++ks2)
            #pragma unroll
            for (int j = 0; j < 4; ++j) {
                unsigned vv = vB[dt][ks2].u[j];
                ym[ks2][2*j]   += blo(vv) * ulv;
                ym[ks2][2*j+1] += bhi(vv) * ulv;
            }
    }
    #pragma unroll
    for (int ks2 = 0; ks2 < 2; ++ks2)
        #pragma unroll
        for (int m = 0; m < 8; ++m) {
            float v = ym[ks2][m];
            v += __shfl_xor(v, 1); v += __shfl_xor(v, 2);
            v += __shfl_xor(v, 4); v += __shfl_xor(v, 8);
            ym[ks2][m] = v;
        }

    __syncthreads();   // ALL waves done reading xs -> overlays become safe

    // ======== logit[n] = P.y ========
    #pragma unroll
    for (int a = 0; a < 4; ++a) {
        float lg = 0.f;
        #pragma unroll
        for (int ks2 = 0; ks2 < 2; ++ks2)
            #pragma unroll
            for (int j = 0; j < 4; ++j) {
                unsigned pv = pA[a][ks2].u[j];
                lg += blo(pv) * ym[ks2][2*j] + bhi(pv) * ym[ks2][2*j+1];
            }
        lg += __shfl_xor(lg, 16);
        lg += __shfl_xor(lg, 32);
        if (quad == 0) logitp[w*64 + a*16 + l15] = lg;
    }
    __syncthreads();

    if (tid < 64) {
        float lg = c0[0];
        #pragma unroll
        for (int ww = 0; ww < 8; ++ww) lg += logitp[ww*64 + tid];
        float gt = 1.0f / (1.0f + __expf(-lg));
        gatev[tid] = gt;
        float s = gt;
        s += __shfl_xor(s, 1);  s += __shfl_xor(s, 2);  s += __shfl_xor(s, 4);
        s += __shfl_xor(s, 8);  s += __shfl_xor(s, 16); s += __shfl_xor(s, 32);
        if (tid == 0) sgsp[0] = s;
    }
    __syncthreads();

    // ======== t = P^T.gate ; wctx[d] = V^T.t -> wctxs ========
    {
        float gl[4];
        #pragma unroll
        for (int a = 0; a < 4; ++a) gl[a] = gatev[a*16 + l15];
        float tm[2][8];
        #pragma unroll
        for (int ks2 = 0; ks2 < 2; ++ks2)
            #pragma unroll
            for (int j = 0; j < 4; ++j) {
                float t0 = 0.f, t1 = 0.f;
                #pragma unroll
                for (int a = 0; a < 4; ++a) {
                    unsigned pv = pA[a][ks2].u[j];
                    t0 += blo(pv) * gl[a];
                    t1 += bhi(pv) * gl[a];
                }
                tm[ks2][2*j] = t0; tm[ks2][2*j+1] = t1;
            }
        #pragma unroll
        for (int ks2 = 0; ks2 < 2; ++ks2)
            #pragma unroll
            for (int m = 0; m < 8; ++m) {
                float v = tm[ks2][m];
                v += __shfl_xor(v, 1); v += __shfl_xor(v, 2);
                v += __shfl_xor(v, 4); v += __shfl_xor(v, 8);
                tm[ks2][m] = v;
            }
        #pragma unroll
        for (int dt = 0; dt < 4; ++dt) {
            float s = 0.f;
            #pragma unroll
            for (int ks2 = 0; ks2 < 2; ++ks2)
                #pragma unroll
                for (int j = 0; j < 4; ++j) {
                    unsigned vv = vB[dt][ks2].u[j];
                    s += blo(vv) * tm[ks2][2*j] + bhi(vv) * tm[ks2][2*j+1];
                }
            s += __shfl_xor(s, 16);
            s += __shfl_xor(s, 32);
            if (quad == 0) wctxs[h*64 + dt*16 + l15] = s;
        }
    }
    __syncthreads();

    // ======== out-proj via MFMA GEMV: out[g][e] = wctx.Wo[e,:] + sgs*bo[e] ========
    {
        const float sgv = sgsp[0];
        f32x4 oc[4];
        #pragma unroll
        for (int et = 0; et < 4; ++et) oc[et] = (f32x4){0.f,0.f,0.f,0.f};
        const unsigned short* wr = wo_bf + (size_t)(w*64) * 512;  // this wave: e in [w*64, w*64+64)
        #pragma unroll 4
        for (int ks = 0; ks < 16; ++ks) {
            // B-frag: broadcast wctx chunk (identical for all 16 "n" rows)
            float4 ca = *(const float4*)(wctxs + ks*32 + quad*8);
            float4 cb = *(const float4*)(wctxs + ks*32 + quad*8 + 4);
            U8 bf;
            bf.u[0] = pack2(ca.x, ca.y); bf.u[1] = pack2(ca.z, ca.w);
            bf.u[2] = pack2(cb.x, cb.y); bf.u[3] = pack2(cb.z, cb.w);
            #pragma unroll
            for (int et = 0; et < 4; ++et) {
                short8 af = *(const short8*)(wr + (size_t)(et*16 + l15)*512 + ks*32 + quad*8);
                oc[et] = __builtin_amdgcn_mfma_f32_16x16x32_bf16(af, bf.s, oc[et], 0,0,0);
            }
        }
        if (l15 == 0) {
            #pragma unroll
            for (int et = 0; et < 4; ++et) {
                const int e0 = w*64 + et*16 + quad*4;     // 16B-aligned
                float4 bv = *(const float4*)(bo + e0);
                float4 ov;
                ov.x = oc[et][0] + sgv * bv.x;
                ov.y = oc[et][1] + sgv * bv.y;
                ov.z = oc[et][2] + sgv * bv.z;
                ov.w = oc[et][3] + sgv * bv.w;
                *(float4*)(out + (size_t)g*512 + e0) = ov;
            }
        }
    }
}

extern "C" void kernel_launch(void* const* d_in, const int* in_sizes, int n_in,
                              void* d_out, int out_size, void* d_ws, size_t ws_size,
                              hipStream_t stream) {
    const float* x    = (const float*)d_in[0];
    // d_in[1] = batch (int64) — unused: graphs are equal-sized (64 nodes)
    const float* wqkv = (const float*)d_in[2];
    const float* bqkv = (const float*)d_in[3];
    const float* wo   = (const float*)d_in[4];
    const float* bo   = (const float*)d_in[5];
    const float* gw   = (const float*)d_in[6];
    const float* gb   = (const float*)d_in[7];
    float* out = (float*)d_out;

    char* ws = (char*)d_ws;
    unsigned short* wqkv_bf = (unsigned short*)(ws + WQKV_OFF);
    unsigned short* wo_bf   = (unsigned short*)(ws + WO_OFF);
    float*          upart   = (float*)(ws + UPART_OFF);
    float*          c0_ws   = (float*)(ws + C0_OFF);

    const int total = in_sizes[0] / D_;  // 65536 nodes
    const int G     = total / 64;        // 1024 graphs

    hipLaunchKernelGGL(aux_kernel, dim3(1041), dim3(256), 0, stream,
                       wqkv, wo, gw, bo, gb, wqkv_bf, upart, c0_ws);
    hipLaunchKernelGGL(attn_full_kernel, dim3(G), dim3(512), 0, stream,
                       x, wqkv_bf, bqkv, wo_bf, bo, upart, c0_ws, out);
}